// Round 5
// baseline (463.061 us; speedup 1.0000x reference)
//
#include <hip/hip_runtime.h>
#include <cstdint>
#include <cstddef>

// Problem dims (fixed by reference)
#define BDIM 512
#define SDIM 64
#define DDIM 256
#define D2   512
#define NNODE 100000
#define NM1  99999   // logits columns

typedef short short8 __attribute__((ext_vector_type(8)));
typedef float f32x4 __attribute__((ext_vector_type(4)));

__device__ __forceinline__ unsigned short f2bf(float f) {
  unsigned int u = __float_as_uint(f);
  u += 0x7FFFu + ((u >> 16) & 1u);   // RNE
  return (unsigned short)(u >> 16);
}

// ---------------------------------------------------------------------------
// Kernel 1: per-batch prep. Only row s* = alias[b, rm-1] is used downstream.
// av[b, 0:256] = adj_in[b,s*,:] @ emb[item[b,:]]; av[b,256:512] = adj_out row.
// ---------------------------------------------------------------------------
__global__ __launch_bounds__(256) void prep_kernel(
    const float* __restrict__ emb, const float* __restrict__ adj_in,
    const float* __restrict__ adj_out, const float* __restrict__ mask,
    const int* __restrict__ item, const int* __restrict__ alias_,
    float* __restrict__ av) {
  __shared__ float a_in[SDIM], a_out[SDIM];
  __shared__ int it[SDIM];
  __shared__ int s_star;
  const int b = blockIdx.x, t = threadIdx.x;
  if (t < SDIM) it[t] = item[b * SDIM + t];
  if (t < 64) {
    float m = mask[b * SDIM + t];
#pragma unroll
    for (int off = 32; off > 0; off >>= 1) m += __shfl_down(m, off, 64);
    if (t == 0) {
      int rm = (int)m;                     // matches astype(int32) truncation
      s_star = alias_[b * SDIM + rm - 1];
    }
  }
  __syncthreads();
  const int ss = s_star;
  if (t < SDIM) a_in[t] = adj_in[((size_t)b * SDIM + ss) * SDIM + t];
  else if (t < 2 * SDIM) a_out[t - SDIM] = adj_out[((size_t)b * SDIM + ss) * SDIM + (t - SDIM)];
  __syncthreads();
  const int d = t;  // 256 threads == DDIM
  float ai = 0.f, ao = 0.f;
#pragma unroll 8
  for (int j = 0; j < SDIM; j++) {
    float e = emb[(size_t)it[j] * DDIM + d];  // coalesced across d
    ai = fmaf(a_in[j], e, ai);
    ao = fmaf(a_out[j], e, ao);
  }
  av[(size_t)b * D2 + d] = ai;
  av[(size_t)b * D2 + DDIM + d] = ao;
}

// ---------------------------------------------------------------------------
// Kernels 2+3: fp32 GEMM, tile 32(M) x 64(N), 256 threads, 4x2 micro-tile.
// mlp1: O = relu(A@W1) f32;  mlp2: O = (A@W2) -> bf16.
// ---------------------------------------------------------------------------
template <int N, bool RELU, bool OUTBF16>
__global__ __launch_bounds__(256) void mlp_kernel(
    const float* __restrict__ A, const float* __restrict__ W,
    float* __restrict__ Of, unsigned short* __restrict__ Ob) {
  __shared__ float As[32][36];   // [m][k]
  __shared__ float Bs[32][68];   // [k][n]
  const int tx = threadIdx.x, ty = threadIdx.y;  // 16x16
  const int t = ty * 16 + tx;
  const int row0 = blockIdx.y * 32, col0 = blockIdx.x * 64;
  const int ar = t >> 3, ac = (t & 7) * 4;   // As: 32x32 = 4 f32/thread
  const int kr = t >> 4, bc = (t & 15) * 4;  // Bs: 32x64 = 8 f32/thread
  float acc[2][4];
#pragma unroll
  for (int i = 0; i < 2; i++)
#pragma unroll
    for (int j = 0; j < 4; j++) acc[i][j] = 0.f;

  for (int k0 = 0; k0 < D2; k0 += 32) {
    const float4 a4 = *(const float4*)&A[(size_t)(row0 + ar) * D2 + k0 + ac];
    const float4 b4a = *(const float4*)&W[(size_t)(k0 + kr) * N + col0 + bc];
    const float4 b4b = *(const float4*)&W[(size_t)(k0 + kr + 16) * N + col0 + bc];
    *(float4*)&As[ar][ac] = a4;
    *(float4*)&Bs[kr][bc] = b4a;
    *(float4*)&Bs[kr + 16][bc] = b4b;
    __syncthreads();
#pragma unroll
    for (int k = 0; k < 32; k++) {
      const float a0 = As[ty * 2][k];
      const float a1 = As[ty * 2 + 1][k];
      const float4 bv = *(const float4*)&Bs[k][tx * 4];
      acc[0][0] = fmaf(a0, bv.x, acc[0][0]); acc[0][1] = fmaf(a0, bv.y, acc[0][1]);
      acc[0][2] = fmaf(a0, bv.z, acc[0][2]); acc[0][3] = fmaf(a0, bv.w, acc[0][3]);
      acc[1][0] = fmaf(a1, bv.x, acc[1][0]); acc[1][1] = fmaf(a1, bv.y, acc[1][1]);
      acc[1][2] = fmaf(a1, bv.z, acc[1][2]); acc[1][3] = fmaf(a1, bv.w, acc[1][3]);
    }
    __syncthreads();
  }
#pragma unroll
  for (int i = 0; i < 2; i++) {
    const int row = row0 + ty * 2 + i;
    const int col = col0 + tx * 4;
    float4 r4;
    r4.x = acc[i][0]; r4.y = acc[i][1]; r4.z = acc[i][2]; r4.w = acc[i][3];
    if constexpr (RELU) {
      r4.x = fmaxf(r4.x, 0.f); r4.y = fmaxf(r4.y, 0.f);
      r4.z = fmaxf(r4.z, 0.f); r4.w = fmaxf(r4.w, 0.f);
    }
    if constexpr (OUTBF16) {
      ushort4 p;
      p.x = f2bf(r4.x); p.y = f2bf(r4.y); p.z = f2bf(r4.z); p.w = f2bf(r4.w);
      *(ushort4*)&Ob[(size_t)row * N + col] = p;
    } else {
      *(float4*)&Of[(size_t)row * N + col] = r4;
    }
  }
}

// ---------------------------------------------------------------------------
// Kernel 4: logits[512, 99999] = last_h(bf16) @ emb[1:]^T  (bf16 MFMA)
// Round-5 re-blocking for DRAM page locality of the write stream:
//   grid (391 n-chunks x 2 m-halves); block = 256 rows x 256 cols, processed
//   as 4 consecutive 64-col sub-tiles. Consecutive sub-tiles write adjacent
//   256B segments of the same output rows back-to-back -> ~1KB contiguous
//   per row-page before L2 eviction (~4x fewer DRAM page activates vs the
//   round-4 one-shot 64-col strips that burst 256B into 512 scattered pages
//   per block -- the suspected ~100us stall).
//   - B sub-tile (64 emb rows, K=256) staged per sub-tile (f32->bf16, LDS).
//   - A fragments direct from global (lasth 256KB, L2-resident).
//   - sum-exp accumulates in registers across sub-tiles; one shfl-reduce +
//     LDS + coalesced part-store at the end (no global atomics; r4 lesson).
//   - emb read 2x total (one per m-half): FETCH ~112MB, cheap vs page wins.
// ---------------------------------------------------------------------------
#define NT    64
#define BPAD  264
#define NCHUNK 391   // ceil(99999 / 256); chunk = 4 sub-tiles of 64 cols

__global__ __launch_bounds__(512, 4) void logits_gemm(
    const unsigned short* __restrict__ Abf,  // [512,256] bf16
    const float* __restrict__ emb,           // [100000,256] f32
    float* __restrict__ out,                 // d_out: [0]=loss, [1..]=logits
    float* __restrict__ part) {              // [NCHUNK][512] partial sum-exp
  __shared__ short Bs[NT * BPAD];            // 33792 B
  __shared__ float rse_s[256];               // 1 KB
  const int t = threadIdx.x;
  const int lane = t & 63, w = t >> 6;       // 8 waves
  const int nchunk = blockIdx.x;             // 0..390
  const int mbase = blockIdx.y * 256;        // 0 or 256
  const int wm = w * 32;                     // local row base of wave
  const int c = lane & 15, q = lane >> 4;

  float s8[8];
#pragma unroll
  for (int i = 0; i < 8; i++) s8[i] = 0.f;

#pragma unroll 1
  for (int st = 0; st < 4; st++) {
    const int nbase = nchunk * 256 + st * NT;

    __syncthreads();   // protect Bs against previous sub-tile's readers
    // ---- stage B: 64 emb rows (cols n+1), f32 -> bf16.
    {
      const int row = t >> 3;
      const int cb = (t & 7) * 4;
      int er = nbase + row + 1;
      if (er > NM1) er = NM1;  // clamp; invalid cols masked in epilogue
      const float* src = emb + (size_t)er * DDIM;
      short* dst = &Bs[row * BPAD];
#pragma unroll
      for (int j = 0; j < 8; j++) {
        const float4 v = *(const float4*)(src + j * 32 + cb);
        ushort4 p;
        p.x = f2bf(v.x); p.y = f2bf(v.y); p.z = f2bf(v.z); p.w = f2bf(v.w);
        *(ushort4*)&dst[j * 32 + cb] = p;
      }
    }
    __syncthreads();

    f32x4 acc[2][4];
#pragma unroll
    for (int mi = 0; mi < 2; mi++)
#pragma unroll
      for (int ni = 0; ni < 4; ni++) acc[mi][ni] = (f32x4){0.f, 0.f, 0.f, 0.f};

#pragma unroll
    for (int ks = 0; ks < 8; ks++) {   // K = 256 in steps of 32
      short8 afr[2], bfr[4];
#pragma unroll
      for (int mi = 0; mi < 2; mi++)
        afr[mi] = *(const short8*)(Abf +
            (size_t)(mbase + wm + mi * 16 + c) * DDIM + ks * 32 + q * 8);
#pragma unroll
      for (int ni = 0; ni < 4; ni++)
        bfr[ni] = *(const short8*)&Bs[(ni * 16 + c) * BPAD + ks * 32 + q * 8];
#pragma unroll
      for (int mi = 0; mi < 2; mi++)
#pragma unroll
        for (int ni = 0; ni < 4; ni++)
          acc[mi][ni] = __builtin_amdgcn_mfma_f32_16x16x32_bf16(
              afr[mi], bfr[ni], acc[mi][ni], 0, 0, 0);
    }

    // ---- epilogue for this sub-tile: stores + register sum-exp accumulate.
    const bool full = (nbase + NT <= NM1);
#pragma unroll
    for (int mi = 0; mi < 2; mi++) {
#pragma unroll
      for (int r = 0; r < 4; r++) {
        const int grow = mbase + wm + mi * 16 + q * 4 + r;  // C/D row=q*4+reg
        float s = 0.f;
        if (full) {
#pragma unroll
          for (int ni = 0; ni < 4; ni++) {
            const float v = acc[mi][ni][r];
            out[1 + (size_t)grow * NM1 + nbase + ni * 16 + c] = v;
            s += __expf(v);
          }
        } else {
#pragma unroll
          for (int ni = 0; ni < 4; ni++) {
            const int col = nbase + ni * 16 + c;
            if (col < NM1) {
              const float v = acc[mi][ni][r];
              out[1 + (size_t)grow * NM1 + col] = v;
              s += __expf(v);
            }
          }
        }
        s8[mi * 4 + r] += s;
      }
    }
  }

  // ---- one reduce over the 16 col-lanes, LDS, coalesced part store.
#pragma unroll
  for (int mi = 0; mi < 2; mi++) {
#pragma unroll
    for (int r = 0; r < 4; r++) {
      float s = s8[mi * 4 + r];
#pragma unroll
      for (int msk = 1; msk < 16; msk <<= 1) s += __shfl_xor(s, msk, 64);
      if (c == 0) rse_s[wm + mi * 16 + q * 4 + r] = s;
    }
  }
  __syncthreads();
  if (t < 256) part[(size_t)nchunk * BDIM + mbase + t] = rse_s[t];
}

// ---------------------------------------------------------------------------
// Kernel 5a: per-row reduce of partial sum-exps (L2-resident, 800 KB) and
// lossv[b] = log(sumexp[b]) - logits[b, tar[b]-1].
// ---------------------------------------------------------------------------
__global__ __launch_bounds__(256) void rse_loss_kernel(
    const float* __restrict__ part, const float* __restrict__ out,
    const int* __restrict__ tar, float* __restrict__ lossv) {
  const int b = blockIdx.x;   // 512 blocks, one per row
  const int t = threadIdx.x;  // 256
  float s = 0.f;
  for (int j = t; j < NCHUNK; j += 256)
    s += part[(size_t)j * BDIM + b];
  __shared__ float red[4];
#pragma unroll
  for (int off = 32; off > 0; off >>= 1) s += __shfl_down(s, off, 64);
  if ((t & 63) == 0) red[t >> 6] = s;
  __syncthreads();
  if (t == 0) {
    const float tot = red[0] + red[1] + red[2] + red[3];
    const int tt = tar[b];
    const float lg = out[1 + (size_t)b * NM1 + (tt - 1)];
    lossv[b] = logf(tot) - lg;
  }
}

// ---------------------------------------------------------------------------
// Kernel 5b: out[0] = mean(lossv)
// ---------------------------------------------------------------------------
__global__ __launch_bounds__(512) void loss_final_kernel(
    float* __restrict__ out, const float* __restrict__ lossv) {
  __shared__ float red[512];
  const int t = threadIdx.x;
  red[t] = lossv[t];
  __syncthreads();
  for (int stride = 256; stride > 0; stride >>= 1) {
    if (t < stride) red[t] += red[t + stride];
    __syncthreads();
  }
  if (t == 0) out[0] = red[0] / (float)BDIM;
}

// ---------------------------------------------------------------------------
extern "C" void kernel_launch(void* const* d_in, const int* in_sizes, int n_in,
                              void* d_out, int out_size, void* d_ws, size_t ws_size,
                              hipStream_t stream) {
  const float* emb     = (const float*)d_in[0];
  const float* W1      = (const float*)d_in[1];
  const float* W2      = (const float*)d_in[2];
  const float* adj_in  = (const float*)d_in[3];
  const float* adj_out = (const float*)d_in[4];
  const float* mask    = (const float*)d_in[5];
  const int*   item    = (const int*)d_in[6];
  const int*   alias_  = (const int*)d_in[7];
  const int*   tar     = (const int*)d_in[8];
  float* out = (float*)d_out;

  char* ws = (char*)d_ws;
  float* av            = (float*)(ws);                 // 512*512*4 = 1 MB
  float* h1            = (float*)(ws + 1048576);       // 512*512*4 = 1 MB
  unsigned short* lasth = (unsigned short*)(ws + 2097152); // 512*256*2 = 256 KB
  float* part          = (float*)(ws + 2359296);       // 391*512*4 = 800 KB
  float* lossv         = (float*)(ws + 5560320);       // 512*4

  prep_kernel<<<BDIM, 256, 0, stream>>>(emb, adj_in, adj_out, mask, item, alias_, av);
  mlp_kernel<D2, true, false><<<dim3(8, 16), dim3(16, 16), 0, stream>>>(av, W1, h1, nullptr);
  mlp_kernel<DDIM, false, true><<<dim3(4, 16), dim3(16, 16), 0, stream>>>(h1, W2, nullptr, lasth);
  logits_gemm<<<dim3(NCHUNK, 2), 512, 0, stream>>>(lasth, emb, out, part);
  rse_loss_kernel<<<BDIM, 256, 0, stream>>>(part, out, tar, lossv);
  loss_final_kernel<<<1, 512, 0, stream>>>(out, lossv);
}

// Round 6
// 448.772 us; speedup vs baseline: 1.0318x; 1.0318x over previous
//
#include <hip/hip_runtime.h>
#include <cstdint>
#include <cstddef>

// Problem dims (fixed by reference)
#define BDIM 512
#define SDIM 64
#define DDIM 256
#define D2   512
#define NNODE 100000
#define NM1  99999   // logits columns

typedef short short8 __attribute__((ext_vector_type(8)));
typedef float f32x4 __attribute__((ext_vector_type(4)));

__device__ __forceinline__ unsigned short f2bf(float f) {
  unsigned int u = __float_as_uint(f);
  u += 0x7FFFu + ((u >> 16) & 1u);   // RNE
  return (unsigned short)(u >> 16);
}

// ---------------------------------------------------------------------------
// Kernel 1: per-batch prep. Only row s* = alias[b, rm-1] is used downstream.
// av[b, 0:256] = adj_in[b,s*,:] @ emb[item[b,:]]; av[b,256:512] = adj_out row.
// ---------------------------------------------------------------------------
__global__ __launch_bounds__(256) void prep_kernel(
    const float* __restrict__ emb, const float* __restrict__ adj_in,
    const float* __restrict__ adj_out, const float* __restrict__ mask,
    const int* __restrict__ item, const int* __restrict__ alias_,
    float* __restrict__ av) {
  __shared__ float a_in[SDIM], a_out[SDIM];
  __shared__ int it[SDIM];
  __shared__ int s_star;
  const int b = blockIdx.x, t = threadIdx.x;
  if (t < SDIM) it[t] = item[b * SDIM + t];
  if (t < 64) {
    float m = mask[b * SDIM + t];
#pragma unroll
    for (int off = 32; off > 0; off >>= 1) m += __shfl_down(m, off, 64);
    if (t == 0) {
      int rm = (int)m;                     // matches astype(int32) truncation
      s_star = alias_[b * SDIM + rm - 1];
    }
  }
  __syncthreads();
  const int ss = s_star;
  if (t < SDIM) a_in[t] = adj_in[((size_t)b * SDIM + ss) * SDIM + t];
  else if (t < 2 * SDIM) a_out[t - SDIM] = adj_out[((size_t)b * SDIM + ss) * SDIM + (t - SDIM)];
  __syncthreads();
  const int d = t;  // 256 threads == DDIM
  float ai = 0.f, ao = 0.f;
#pragma unroll 8
  for (int j = 0; j < SDIM; j++) {
    float e = emb[(size_t)it[j] * DDIM + d];  // coalesced across d
    ai = fmaf(a_in[j], e, ai);
    ao = fmaf(a_out[j], e, ao);
  }
  av[(size_t)b * D2 + d] = ai;
  av[(size_t)b * D2 + DDIM + d] = ao;
}

// ---------------------------------------------------------------------------
// Kernels 2+3: fp32 GEMM, tile 32(M) x 64(N), 256 threads, 4x2 micro-tile.
// mlp1: O = relu(A@W1) f32;  mlp2: O = (A@W2) -> bf16.
// ---------------------------------------------------------------------------
template <int N, bool RELU, bool OUTBF16>
__global__ __launch_bounds__(256) void mlp_kernel(
    const float* __restrict__ A, const float* __restrict__ W,
    float* __restrict__ Of, unsigned short* __restrict__ Ob) {
  __shared__ float As[32][36];   // [m][k]
  __shared__ float Bs[32][68];   // [k][n]
  const int tx = threadIdx.x, ty = threadIdx.y;  // 16x16
  const int t = ty * 16 + tx;
  const int row0 = blockIdx.y * 32, col0 = blockIdx.x * 64;
  const int ar = t >> 3, ac = (t & 7) * 4;   // As: 32x32 = 4 f32/thread
  const int kr = t >> 4, bc = (t & 15) * 4;  // Bs: 32x64 = 8 f32/thread
  float acc[2][4];
#pragma unroll
  for (int i = 0; i < 2; i++)
#pragma unroll
    for (int j = 0; j < 4; j++) acc[i][j] = 0.f;

  for (int k0 = 0; k0 < D2; k0 += 32) {
    const float4 a4 = *(const float4*)&A[(size_t)(row0 + ar) * D2 + k0 + ac];
    const float4 b4a = *(const float4*)&W[(size_t)(k0 + kr) * N + col0 + bc];
    const float4 b4b = *(const float4*)&W[(size_t)(k0 + kr + 16) * N + col0 + bc];
    *(float4*)&As[ar][ac] = a4;
    *(float4*)&Bs[kr][bc] = b4a;
    *(float4*)&Bs[kr + 16][bc] = b4b;
    __syncthreads();
#pragma unroll
    for (int k = 0; k < 32; k++) {
      const float a0 = As[ty * 2][k];
      const float a1 = As[ty * 2 + 1][k];
      const float4 bv = *(const float4*)&Bs[k][tx * 4];
      acc[0][0] = fmaf(a0, bv.x, acc[0][0]); acc[0][1] = fmaf(a0, bv.y, acc[0][1]);
      acc[0][2] = fmaf(a0, bv.z, acc[0][2]); acc[0][3] = fmaf(a0, bv.w, acc[0][3]);
      acc[1][0] = fmaf(a1, bv.x, acc[1][0]); acc[1][1] = fmaf(a1, bv.y, acc[1][1]);
      acc[1][2] = fmaf(a1, bv.z, acc[1][2]); acc[1][3] = fmaf(a1, bv.w, acc[1][3]);
    }
    __syncthreads();
  }
#pragma unroll
  for (int i = 0; i < 2; i++) {
    const int row = row0 + ty * 2 + i;
    const int col = col0 + tx * 4;
    float4 r4;
    r4.x = acc[i][0]; r4.y = acc[i][1]; r4.z = acc[i][2]; r4.w = acc[i][3];
    if constexpr (RELU) {
      r4.x = fmaxf(r4.x, 0.f); r4.y = fmaxf(r4.y, 0.f);
      r4.z = fmaxf(r4.z, 0.f); r4.w = fmaxf(r4.w, 0.f);
    }
    if constexpr (OUTBF16) {
      ushort4 p;
      p.x = f2bf(r4.x); p.y = f2bf(r4.y); p.z = f2bf(r4.z); p.w = f2bf(r4.w);
      *(ushort4*)&Ob[(size_t)row * N + col] = p;
    } else {
      *(float4*)&Of[(size_t)row * N + col] = r4;
    }
  }
}

// ---------------------------------------------------------------------------
// Kernel 4: logits[512, 99999] = last_h(bf16) @ emb[1:]^T  (bf16 MFMA)
// Round-6: deferred-store re-blocking to merge the misaligned write stream.
//   grid (4 m-quarters FAST axis, 391 n-chunks); block = 128 rows x 256 cols.
//   All 4 64-col sub-tiles are computed first (acc[4 st][4 ni] = 64 VGPR,
//   wave = 16 rows), THEN each row's 16 x 64B segments are stored as 16
//   back-to-back instructions = 1 KB temporally-contiguous run -> L2 merges
//   all interior partial lines (r5 lesson: merging only happens for stores
//   that are back-to-back in time from the same wave; sub-tile-spaced stores
//   re-dirty evicted boundary lines -> WRITE grew 237->270 MB).
//   m-quarter as fast grid axis: the 4 co-dispatched quarters of one nchunk
//   read the SAME emb sub-tiles near-simultaneously (L3 broadcast) and write
//   the same col-range (DRAM page coherent).
//   No global atomics (r4 lesson). VGPR ~105 <= 128 -> 4 waves/SIMD.
// ---------------------------------------------------------------------------
#define NT    64
#define BPAD  264
#define NCHUNK 391   // ceil(99999 / 256); chunk = 4 sub-tiles of 64 cols

__global__ __launch_bounds__(512, 4) void logits_gemm(
    const unsigned short* __restrict__ Abf,  // [512,256] bf16
    const float* __restrict__ emb,           // [100000,256] f32
    float* __restrict__ out,                 // d_out: [0]=loss, [1..]=logits
    float* __restrict__ part) {              // [NCHUNK][512] partial sum-exp
  __shared__ short Bs[NT * BPAD];            // 33792 B
  __shared__ float rse_s[128];               // 512 B
  const int t = threadIdx.x;
  const int lane = t & 63, w = t >> 6;       // 8 waves
  const int mbase = blockIdx.x * 128;        // m-quarter: FAST grid axis
  const int nchunk = blockIdx.y;             // 0..390
  const int c = lane & 15, q = lane >> 4;
  const int wrow = w * 16;                   // wave's 16-row slice

  f32x4 acc[4][4];                           // [sub-tile][ni] = 64 VGPR
#pragma unroll
  for (int st = 0; st < 4; st++)
#pragma unroll
    for (int ni = 0; ni < 4; ni++) acc[st][ni] = (f32x4){0.f, 0.f, 0.f, 0.f};

  // ---- compute all 4 sub-tiles, stores deferred ----
#pragma unroll
  for (int st = 0; st < 4; st++) {
    const int nbase = nchunk * 256 + st * NT;

    __syncthreads();   // protect Bs against previous sub-tile's readers
    {  // stage B: 64 emb rows (cols n+1), f32 -> bf16
      const int row = t >> 3;
      const int cb = (t & 7) * 4;
      int er = nbase + row + 1;
      if (er > NM1) er = NM1;  // clamp; invalid cols masked at store time
      const float* src = emb + (size_t)er * DDIM;
      short* dst = &Bs[row * BPAD];
#pragma unroll
      for (int j = 0; j < 8; j++) {
        const float4 v = *(const float4*)(src + j * 32 + cb);
        ushort4 p;
        p.x = f2bf(v.x); p.y = f2bf(v.y); p.z = f2bf(v.z); p.w = f2bf(v.w);
        *(ushort4*)&dst[j * 32 + cb] = p;
      }
    }
    __syncthreads();

#pragma unroll
    for (int ks = 0; ks < 8; ks++) {   // K = 256 in steps of 32
      const short8 afr = *(const short8*)(Abf +
          (size_t)(mbase + wrow + c) * DDIM + ks * 32 + q * 8);
      short8 bfr[4];
#pragma unroll
      for (int ni = 0; ni < 4; ni++)
        bfr[ni] = *(const short8*)&Bs[(ni * 16 + c) * BPAD + ks * 32 + q * 8];
#pragma unroll
      for (int ni = 0; ni < 4; ni++)
        acc[st][ni] = __builtin_amdgcn_mfma_f32_16x16x32_bf16(
            afr, bfr[ni], acc[st][ni], 0, 0, 0);
    }
  }

  // ---- store phase: per row, 16 back-to-back 64B segments = 1 KB run ----
  float s4[4];
#pragma unroll
  for (int r = 0; r < 4; r++) s4[r] = 0.f;

  const int cbase = nchunk * 256;
  if (cbase + 256 <= NM1) {          // fast path: every col valid
#pragma unroll
    for (int r = 0; r < 4; r++) {
      const int grow = mbase + wrow + q * 4 + r;   // C/D: row = q*4+reg
      float* orow = out + 1 + (size_t)grow * NM1 + cbase + c;
      float s = 0.f;
#pragma unroll
      for (int st = 0; st < 4; st++) {
#pragma unroll
        for (int ni = 0; ni < 4; ni++) {
          const float v = acc[st][ni][r];
          orow[st * 64 + ni * 16] = v;
          s += __expf(v);
        }
      }
      s4[r] = s;
    }
  } else {                           // last chunk: mask col >= NM1
#pragma unroll
    for (int r = 0; r < 4; r++) {
      const int grow = mbase + wrow + q * 4 + r;
      float s = 0.f;
#pragma unroll
      for (int st = 0; st < 4; st++) {
#pragma unroll
        for (int ni = 0; ni < 4; ni++) {
          const int col = cbase + st * 64 + ni * 16 + c;
          if (col < NM1) {
            const float v = acc[st][ni][r];
            out[1 + (size_t)grow * NM1 + col] = v;
            s += __expf(v);
          }
        }
      }
      s4[r] = s;
    }
  }

  // ---- reduce sum-exp over the 16 col-lanes, coalesced part store ----
#pragma unroll
  for (int r = 0; r < 4; r++) {
    float s = s4[r];
#pragma unroll
    for (int msk = 1; msk < 16; msk <<= 1) s += __shfl_xor(s, msk, 64);
    if (c == 0) rse_s[wrow + q * 4 + r] = s;
  }
  __syncthreads();
  if (t < 128) part[(size_t)nchunk * BDIM + mbase + t] = rse_s[t];
}

// ---------------------------------------------------------------------------
// Kernel 5a: per-row reduce of partial sum-exps (L2-resident, 800 KB) and
// lossv[b] = log(sumexp[b]) - logits[b, tar[b]-1].
// ---------------------------------------------------------------------------
__global__ __launch_bounds__(256) void rse_loss_kernel(
    const float* __restrict__ part, const float* __restrict__ out,
    const int* __restrict__ tar, float* __restrict__ lossv) {
  const int b = blockIdx.x;   // 512 blocks, one per row
  const int t = threadIdx.x;  // 256
  float s = 0.f;
  for (int j = t; j < NCHUNK; j += 256)
    s += part[(size_t)j * BDIM + b];
  __shared__ float red[4];
#pragma unroll
  for (int off = 32; off > 0; off >>= 1) s += __shfl_down(s, off, 64);
  if ((t & 63) == 0) red[t >> 6] = s;
  __syncthreads();
  if (t == 0) {
    const float tot = red[0] + red[1] + red[2] + red[3];
    const int tt = tar[b];
    const float lg = out[1 + (size_t)b * NM1 + (tt - 1)];
    lossv[b] = logf(tot) - lg;
  }
}

// ---------------------------------------------------------------------------
// Kernel 5b: out[0] = mean(lossv)
// ---------------------------------------------------------------------------
__global__ __launch_bounds__(512) void loss_final_kernel(
    float* __restrict__ out, const float* __restrict__ lossv) {
  __shared__ float red[512];
  const int t = threadIdx.x;
  red[t] = lossv[t];
  __syncthreads();
  for (int stride = 256; stride > 0; stride >>= 1) {
    if (t < stride) red[t] += red[t + stride];
    __syncthreads();
  }
  if (t == 0) out[0] = red[0] / (float)BDIM;
}

// ---------------------------------------------------------------------------
extern "C" void kernel_launch(void* const* d_in, const int* in_sizes, int n_in,
                              void* d_out, int out_size, void* d_ws, size_t ws_size,
                              hipStream_t stream) {
  const float* emb     = (const float*)d_in[0];
  const float* W1      = (const float*)d_in[1];
  const float* W2      = (const float*)d_in[2];
  const float* adj_in  = (const float*)d_in[3];
  const float* adj_out = (const float*)d_in[4];
  const float* mask    = (const float*)d_in[5];
  const int*   item    = (const int*)d_in[6];
  const int*   alias_  = (const int*)d_in[7];
  const int*   tar     = (const int*)d_in[8];
  float* out = (float*)d_out;

  char* ws = (char*)d_ws;
  float* av            = (float*)(ws);                 // 512*512*4 = 1 MB
  float* h1            = (float*)(ws + 1048576);       // 512*512*4 = 1 MB
  unsigned short* lasth = (unsigned short*)(ws + 2097152); // 512*256*2 = 256 KB
  float* part          = (float*)(ws + 2359296);       // 391*512*4 = 800 KB
  float* lossv         = (float*)(ws + 5560320);       // 512*4

  prep_kernel<<<BDIM, 256, 0, stream>>>(emb, adj_in, adj_out, mask, item, alias_, av);
  mlp_kernel<D2, true, false><<<dim3(8, 16), dim3(16, 16), 0, stream>>>(av, W1, h1, nullptr);
  mlp_kernel<DDIM, false, true><<<dim3(4, 16), dim3(16, 16), 0, stream>>>(h1, W2, nullptr, lasth);
  logits_gemm<<<dim3(4, NCHUNK), 512, 0, stream>>>(lasth, emb, out, part);
  rse_loss_kernel<<<BDIM, 256, 0, stream>>>(part, out, tar, lossv);
  loss_final_kernel<<<1, 512, 0, stream>>>(out, lossv);
}